// Round 4
// baseline (383.672 us; speedup 1.0000x reference)
//
#include <hip/hip_runtime.h>

#define U 4096
#define S 8192
#define D 32
#define NUM_REGIONS 128
#define GA 0.1f

#define TU 32      // users per block
#define TI 256     // items per block = 1 per thread (32 VGPRs, holdable!)
#define THREADS 256
#define LCAP 256   // max users per region (expected ~32)

// pin a float4 in VGPRs: asm outputs are non-rematerializable, so the values
// must stay in registers (or scratch — WRITE_SIZE would show scratch, it doesn't)
#define PIN4(v) asm volatile("" : "+v"(v.x), "+v"(v.y), "+v"(v.z), "+v"(v.w))

// ---------------- fused kernel: masked-MSE + region loss ----------------
// Round-0/1/3 evidence: 2 item rows/thread (64 floats) never stayed
// register-resident (VGPR_Count 56/48/60 < 64) => 16 dwordx4 reloads per
// uu-iter = 4.3 GB L2 traffic at ~30 TB/s = the 135us floor. 1 item/thread
// (32 floats) fits the default 64-VGPR budget with room to spare.

__global__ __launch_bounds__(THREADS) void fused_kernel(
    const float* __restrict__ user_emb,
    const float* __restrict__ item_emb,
    const int* __restrict__ train_mask,
    const float* __restrict__ true_qos,
    const float* __restrict__ us_lossweight,
    const int* __restrict__ region_index,
    float* __restrict__ loss_accum,
    float* __restrict__ rl_accum) {
    __shared__ float uemb[TU][D];    // 4 KB user tile
    __shared__ int   ridx[U];        // 16 KB (region-duty blocks only)
    __shared__ int   ulist[LCAP];
    __shared__ int   ucnt;
    __shared__ float part[8][D];
    __shared__ float redsum[D];
    __shared__ float wp[THREADS / 64];

    const int ub = blockIdx.x * TU;  // 128 user tiles  (== NUM_REGIONS)
    const int sb = blockIdx.y * TI;  // 32 item tiles

    // cooperative load of user tile: TU*D = 1024 floats = 256 float4
    {
        const float4* src = (const float4*)(user_emb + (size_t)ub * D);
        ((float4*)&uemb[0][0])[threadIdx.x] = src[threadIdx.x];
    }

    // this thread's single item row: 8 float4 = 32 VGPRs
    const int s0 = sb + threadIdx.x;
    float4 ir[8];
    {
        const float4* ip = (const float4*)(item_emb + (size_t)s0 * D);
        #pragma unroll
        for (int k = 0; k < 8; k++) ir[k] = ip[k];
        #pragma unroll
        for (int k = 0; k < 8; k++) PIN4(ir[k]);
    }
    __syncthreads();

    // streaming loads, software-pipelined one user ahead
    const size_t base0 = (size_t)ub * S + s0;
    int   m_n = train_mask[base0];
    float q_n = true_qos[base0];
    float w_n = us_lossweight[base0];

    float acc = 0.0f;
    #pragma unroll 1
    for (int uu = 0; uu < TU; uu++) {
        int   m = m_n;
        float q = q_n;
        float w = w_n;
        if (uu + 1 < TU) {
            const size_t nb = base0 + (size_t)(uu + 1) * S;
            m_n = train_mask[nb];
            q_n = true_qos[nb];
            w_n = us_lossweight[nb];
        }

        float d0 = 0.0f;
        const float4* ur = (const float4*)&uemb[uu][0];  // broadcast LDS reads
        #pragma unroll
        for (int k = 0; k < 8; k++) {
            float4 uv = ur[k];
            d0 += uv.x * ir[k].x + uv.y * ir[k].y + uv.z * ir[k].z + uv.w * ir[k].w;
        }
        float p = d0 * (float)m;
        float e = p - q;
        acc += w * e * e;
    }

    // wave64 reduce + one atomic per block
    #pragma unroll
    for (int off = 32; off > 0; off >>= 1) acc += __shfl_down(acc, off, 64);
    {
        int lane = threadIdx.x & 63, wid = threadIdx.x >> 6;
        if (lane == 0) wp[wid] = acc;
        __syncthreads();
        if (threadIdx.x == 0) {
            float t = 0.0f;
            #pragma unroll
            for (int i = 0; i < THREADS / 64; i++) t += wp[i];
            atomicAdd(loss_accum, t);
        }
    }

    // ---- region duty: first item-tile column handles region r = blockIdx.x ----
    // These 128 blocks are dispatched first; their extra ~10us hides under the
    // other 3968 blocks' streaming.
    if (blockIdx.y != 0) return;
    const int r = blockIdx.x;

    if (threadIdx.x == 0) ucnt = 0;
    // cooperative load of region_index (16 KB): 4 int4 per thread
    #pragma unroll
    for (int i = 0; i < U / 4 / 256; i++)
        ((int4*)ridx)[threadIdx.x + i * 256] =
            ((const int4*)region_index)[threadIdx.x + i * 256];
    __syncthreads();

    // parallel scan: all 256 threads stride the user list (16 iters)
    for (int u = threadIdx.x; u < U; u += 256) {
        if (ridx[u] == r) {
            int p = atomicAdd(&ucnt, 1);
            if (p < LCAP) ulist[p] = u;
        }
    }
    __syncthreads();

    const int n = min(ucnt, LCAP);
    const int d = threadIdx.x & (D - 1);      // dim 0..31
    const int w8 = threadIdx.x >> 5;          // list stripe 0..7

    // pass 1: region sum over the compact list (~4 iters per stripe)
    float psum = 0.0f;
    for (int i = w8; i < n; i += 8)
        psum += user_emb[ulist[i] * D + d];
    part[w8][d] = psum;
    __syncthreads();
    if (w8 == 0) {
        float sum = 0.0f;
        #pragma unroll
        for (int i = 0; i < 8; i++) sum += part[i][d];
        redsum[d] = sum;
    }
    __syncthreads();

    // pass 2: leave-one-out deviation over the list
    float racc = 0.0f;
    if (n > 1) {
        const float inv = 1.0f / (float)(n - 1);
        const float sd = redsum[d];
        for (int i = w8; i < n; i += 8) {
            float e = user_emb[ulist[i] * D + d];
            racc += fabsf(e - (sd - e) * inv);
        }
    }

    #pragma unroll
    for (int off = 32; off > 0; off >>= 1) racc += __shfl_down(racc, off, 64);
    {
        int lane = threadIdx.x & 63, wid = threadIdx.x >> 6;
        if (lane == 0) wp[wid] = racc;
        __syncthreads();
        if (threadIdx.x == 0) {
            float t = 0.0f;
            #pragma unroll
            for (int i = 0; i < THREADS / 64; i++) t += wp[i];
            atomicAdd(rl_accum, t);
        }
    }
}

__global__ void finalize_kernel(const float* __restrict__ loss_acc,
                                const float* __restrict__ rl_acc,
                                float* __restrict__ out) {
    out[0] = loss_acc[0] + GA * rl_acc[0];
}

extern "C" void kernel_launch(void* const* d_in, const int* in_sizes, int n_in,
                              void* d_out, int out_size, void* d_ws, size_t ws_size,
                              hipStream_t stream) {
    const float* user_emb      = (const float*)d_in[0];
    const float* item_emb      = (const float*)d_in[1];
    const int*   train_mask    = (const int*)d_in[2];
    const float* true_qos      = (const float*)d_in[3];
    const float* us_lossweight = (const float*)d_in[4];
    const int*   region_index  = (const int*)d_in[5];
    float* out = (float*)d_out;

    float* ws       = (float*)d_ws;
    float* loss_acc = ws;          // 1
    float* rl_acc   = ws + 1;      // 1
    hipMemsetAsync(d_ws, 0, 2 * sizeof(float), stream);

    dim3 grid(U / TU, S / TI);     // (128, 32); y==0 blocks also do region duty
    fused_kernel<<<grid, THREADS, 0, stream>>>(
        user_emb, item_emb, train_mask, true_qos, us_lossweight, region_index,
        loss_acc, rl_acc);

    finalize_kernel<<<1, 1, 0, stream>>>(loss_acc, rl_acc, out);
}

// Round 5
// 375.416 us; speedup vs baseline: 1.0220x; 1.0220x over previous
//
#include <hip/hip_runtime.h>

#define U 4096
#define S 8192
#define D 32
#define NUM_REGIONS 128
#define GA 0.1f

#define TU 32      // users per block
#define TI 256     // items per block = 1 per thread
#define UG 8       // user micro-tile: item float4 loaded once per 8 users
#define THREADS 256
#define LCAP 256   // max users per region (expected ~32)

// ---------------- fused kernel: masked-MSE + region loss ----------------
// Rounds 0-4 proved the allocator will NOT keep a 32-float item row live
// across the user loop (VGPR_Count 56/48/60/36, pins+budget hints all
// ignored) => 8 dwordx4 reloads per user = 4.3 GB L2 traffic at the
// ~30 TB/s L2 ceiling = the 135-152us floor. Fix: amortize, don't pin.
// Each item float4 is loaded ONCE per 8-user group (transient 4 VGPRs,
// nothing long-lived to evict): item traffic 4.3 GB -> 537 MB.

__global__ __launch_bounds__(THREADS) void fused_kernel(
    const float* __restrict__ user_emb,
    const float* __restrict__ item_emb,
    const int* __restrict__ train_mask,
    const float* __restrict__ true_qos,
    const float* __restrict__ us_lossweight,
    const int* __restrict__ region_index,
    float* __restrict__ loss_accum,
    float* __restrict__ rl_accum) {
    __shared__ float uemb[TU][D];    // 4 KB user tile
    __shared__ int   ulist[LCAP];    // 1 KB (region-duty blocks)
    __shared__ int   ucnt;
    __shared__ float part[8][D];     // 1 KB
    __shared__ float redsum[D];
    __shared__ float wp[THREADS / 64];

    const int ub = blockIdx.x * TU;  // 128 user tiles (== NUM_REGIONS)
    const int sb = blockIdx.y * TI;  // 32 item tiles

    // cooperative load of user tile: TU*D = 1024 floats = 256 float4
    {
        const float4* src = (const float4*)(user_emb + (size_t)ub * D);
        ((float4*)&uemb[0][0])[threadIdx.x] = src[threadIdx.x];
    }
    __syncthreads();

    const int s0 = sb + threadIdx.x;           // this thread's item
    const float4* ip = (const float4*)(item_emb + (size_t)s0 * D);

    float acc = 0.0f;
    #pragma unroll 1
    for (int g = 0; g < TU; g += UG) {
        // streaming loads for this 8-user group (independent -> good ILP)
        int   m[UG]; float q[UG], w[UG];
        #pragma unroll
        for (int j = 0; j < UG; j++) {
            const size_t b = (size_t)(ub + g + j) * S + s0;
            m[j] = train_mask[b];
            q[j] = true_qos[b];
            w[j] = us_lossweight[b];
        }

        float dsum[UG];
        #pragma unroll
        for (int j = 0; j < UG; j++) dsum[j] = 0.0f;

        // item float4 loaded once, applied to 8 users (L1/L2-hit, amortized)
        #pragma unroll
        for (int k = 0; k < 8; k++) {
            float4 iv = ip[k];
            #pragma unroll
            for (int j = 0; j < UG; j++) {
                float4 uv = *(const float4*)&uemb[g + j][k * 4];  // broadcast
                dsum[j] += uv.x * iv.x + uv.y * iv.y + uv.z * iv.z + uv.w * iv.w;
            }
        }

        #pragma unroll
        for (int j = 0; j < UG; j++) {
            float p = dsum[j] * (float)m[j];
            float e = p - q[j];
            acc += w[j] * e * e;
        }
    }

    // wave64 reduce + one atomic per block
    #pragma unroll
    for (int off = 32; off > 0; off >>= 1) acc += __shfl_down(acc, off, 64);
    {
        int lane = threadIdx.x & 63, wid = threadIdx.x >> 6;
        if (lane == 0) wp[wid] = acc;
        __syncthreads();
        if (threadIdx.x == 0) {
            float t = 0.0f;
            #pragma unroll
            for (int i = 0; i < THREADS / 64; i++) t += wp[i];
            atomicAdd(loss_accum, t);
        }
    }

    // ---- region duty: blockIdx.y==0 blocks handle region r = blockIdx.x ----
    if (blockIdx.y != 0) return;
    const int r = blockIdx.x;

    __syncthreads();                 // wp reads above complete before reuse
    if (threadIdx.x == 0) ucnt = 0;
    __syncthreads();

    // parallel scan straight from global (region_index is 16 KB, L2-resident)
    for (int u = threadIdx.x; u < U; u += 256) {
        if (region_index[u] == r) {
            int p = atomicAdd(&ucnt, 1);
            if (p < LCAP) ulist[p] = u;
        }
    }
    __syncthreads();

    const int n = min(ucnt, LCAP);
    const int d = threadIdx.x & (D - 1);      // dim 0..31
    const int w8 = threadIdx.x >> 5;          // list stripe 0..7

    // pass 1: region sum over the compact list (~4 iters per stripe)
    float psum = 0.0f;
    for (int i = w8; i < n; i += 8)
        psum += user_emb[ulist[i] * D + d];
    part[w8][d] = psum;
    __syncthreads();
    if (w8 == 0) {
        float sum = 0.0f;
        #pragma unroll
        for (int i = 0; i < 8; i++) sum += part[i][d];
        redsum[d] = sum;
    }
    __syncthreads();

    // pass 2: leave-one-out deviation over the list
    float racc = 0.0f;
    if (n > 1) {
        const float inv = 1.0f / (float)(n - 1);
        const float sd = redsum[d];
        for (int i = w8; i < n; i += 8) {
            float e = user_emb[ulist[i] * D + d];
            racc += fabsf(e - (sd - e) * inv);
        }
    }

    #pragma unroll
    for (int off = 32; off > 0; off >>= 1) racc += __shfl_down(racc, off, 64);
    {
        int lane = threadIdx.x & 63, wid = threadIdx.x >> 6;
        if (lane == 0) wp[wid] = racc;
        __syncthreads();
        if (threadIdx.x == 0) {
            float t = 0.0f;
            #pragma unroll
            for (int i = 0; i < THREADS / 64; i++) t += wp[i];
            atomicAdd(rl_accum, t);
        }
    }
}

__global__ void finalize_kernel(const float* __restrict__ loss_acc,
                                const float* __restrict__ rl_acc,
                                float* __restrict__ out) {
    out[0] = loss_acc[0] + GA * rl_acc[0];
}

extern "C" void kernel_launch(void* const* d_in, const int* in_sizes, int n_in,
                              void* d_out, int out_size, void* d_ws, size_t ws_size,
                              hipStream_t stream) {
    const float* user_emb      = (const float*)d_in[0];
    const float* item_emb      = (const float*)d_in[1];
    const int*   train_mask    = (const int*)d_in[2];
    const float* true_qos      = (const float*)d_in[3];
    const float* us_lossweight = (const float*)d_in[4];
    const int*   region_index  = (const int*)d_in[5];
    float* out = (float*)d_out;

    float* ws       = (float*)d_ws;
    float* loss_acc = ws;          // 1
    float* rl_acc   = ws + 1;      // 1
    hipMemsetAsync(d_ws, 0, 2 * sizeof(float), stream);

    dim3 grid(U / TU, S / TI);     // (128, 32); y==0 blocks also do region duty
    fused_kernel<<<grid, THREADS, 0, stream>>>(
        user_emb, item_emb, train_mask, true_qos, us_lossweight, region_index,
        loss_acc, rl_acc);

    finalize_kernel<<<1, 1, 0, stream>>>(loss_acc, rl_acc, out);
}